// Round 5
// baseline (190.989 us; speedup 1.0000x reference)
//
#include <hip/hip_runtime.h>
#include <hip/hip_bf16.h>

// Problem constants (from reference): B,T,L,R,E,F
#define B_ 8
#define T_ 16
#define L_ 128
#define R_ 1024
#define E_ 5
#define F_ 512

typedef short short8 __attribute__((ext_vector_type(8)));
typedef float floatx4 __attribute__((ext_vector_type(4)));

// fp32 -> bf16 bits, round-half-up
__device__ __forceinline__ unsigned short f2bf(float f) {
  unsigned u = __float_as_uint(f);
  return (unsigned short)((u + 0x8000u) >> 16);
}

__device__ __forceinline__ short8 pack8(floatx4 lo, floatx4 hi) {
  short8 v;
  v[0] = (short)f2bf(lo[0]); v[1] = (short)f2bf(lo[1]);
  v[2] = (short)f2bf(lo[2]); v[3] = (short)f2bf(lo[3]);
  v[4] = (short)f2bf(hi[0]); v[5] = (short)f2bf(hi[1]);
  v[6] = (short)f2bf(hi[2]); v[7] = (short)f2bf(hi[3]);
  return v;
}

// async 16B global->LDS DMA; lane i's data lands at ldsbase + i*16
__device__ __forceinline__ void stage16(const float* g, float* lds) {
  __builtin_amdgcn_global_load_lds(
      (const __attribute__((address_space(1))) void*)g,
      (__attribute__((address_space(3))) void*)lds, 16, 0, 0);
}

// pow_e(d): exps = [-3,-2,-1,1,2]; one rsqrt yields all
template <int E>
__device__ __forceinline__ float powE(float d2, float rs) {
  if (E == 0) return rs * rs * rs;
  if (E == 1) return rs * rs;
  if (E == 2) return rs;
  if (E == 3) return d2 * rs;
  return d2;
}

// ---------------------------------------------------------------------------
// Kernel 1: rot = QR(pre_rot).Q (LAPACK Householder convention), then
// new_lig[b,t,l,:] = rot[b,t] @ lig_coord[b,l] + trans[b,t].
// ---------------------------------------------------------------------------
__global__ void prep_kernel(const float* __restrict__ lig_coord,
                            const float* __restrict__ pre_rot,
                            const float* __restrict__ trans,
                            float* __restrict__ new_lig) {
  int bt = blockIdx.x;
  __shared__ float Qs[3][3];
  if (threadIdx.x == 0) {
    float a[3][3], q[3][3];
    #pragma unroll
    for (int i = 0; i < 3; ++i)
      #pragma unroll
      for (int j = 0; j < 3; ++j) {
        a[i][j] = pre_rot[(bt * 3 + i) * 3 + j];
        q[i][j] = (i == j) ? 1.f : 0.f;
      }
    for (int k = 0; k < 3; ++k) {
      float alpha = a[k][k];
      float xn2 = 0.f;
      for (int i = k + 1; i < 3; ++i) xn2 += a[i][k] * a[i][k];
      float nrm = sqrtf(alpha * alpha + xn2);
      if (xn2 > 0.f && nrm > 0.f) {
        float beta = (alpha >= 0.f) ? -nrm : nrm;
        float tau = (beta - alpha) / beta;
        float inv = 1.f / (alpha - beta);
        float v[3] = {0.f, 0.f, 0.f};
        v[k] = 1.f;
        for (int i = k + 1; i < 3; ++i) v[i] = a[i][k] * inv;
        for (int j = k; j < 3; ++j) {
          float w = 0.f;
          for (int i = k; i < 3; ++i) w += v[i] * a[i][j];
          w *= tau;
          for (int i = k; i < 3; ++i) a[i][j] -= w * v[i];
        }
        for (int i = 0; i < 3; ++i) {
          float w = 0.f;
          for (int j = k; j < 3; ++j) w += q[i][j] * v[j];
          w *= tau;
          for (int j = k; j < 3; ++j) q[i][j] -= w * v[j];
        }
      }
    }
    for (int i = 0; i < 3; ++i)
      for (int j = 0; j < 3; ++j) Qs[i][j] = q[i][j];
  }
  __syncthreads();
  int b = bt >> 4;
  int l = threadIdx.x;
  float cx = lig_coord[(b * L_ + l) * 3 + 0];
  float cy = lig_coord[(b * L_ + l) * 3 + 1];
  float cz = lig_coord[(b * L_ + l) * 3 + 2];
  float nx = Qs[0][0] * cx + Qs[0][1] * cy + Qs[0][2] * cz + trans[bt * 3 + 0];
  float ny = Qs[1][0] * cx + Qs[1][1] * cy + Qs[1][2] * cz + trans[bt * 3 + 1];
  float nz = Qs[2][0] * cx + Qs[2][1] * cy + Qs[2][2] * cz + trans[bt * 3 + 2];
  float* o = new_lig + ((size_t)bt * L_ + l) * 3;
  o[0] = nx; o[1] = ny; o[2] = nz;
}

// ---------------------------------------------------------------------------
// Kernel 2 (FUSED): per block (b,e,rt): GEMM tile atn_e[l, r0:r0+64] (R4's
// proven DMA double-buffered mainloop), then epilogue applies pow_e(d[t,l,r])
// and reduces over r in-register (16-lane shfl) -> p2[b,t,e*16+rt,l].
// Works because U = sum_e sum_lr atn_e * pow_e -- e-terms are independent.
// Eliminates the 21MB atn write + 21MB read and the reduce dispatch.
// d-math is recomputed per-e (5x) but hides under staging waits.
// ---------------------------------------------------------------------------
__launch_bounds__(256)
__global__ void fused_kernel(const float* __restrict__ lig_feat,
                             const float* __restrict__ rec_feat,
                             const float* __restrict__ new_lig,
                             const float* __restrict__ rec_coord,
                             const int* __restrict__ lig_counts,
                             const int* __restrict__ rec_counts,
                             float* __restrict__ p2) {
  const int rt = blockIdx.x;    // 0..15
  const int e  = blockIdx.y;    // 0..4
  const int b  = blockIdx.z;    // 0..7
  const int r0 = rt * 64;
  const int tid = threadIdx.x;
  const int k80 = e * 16 + rt;
  const int recN = rec_counts[b];

  if (r0 >= recN) {             // fully masked tile: zero our p2 slice
    for (int i = tid; i < T_ * L_; i += 256) {
      int t = i >> 7, l = i & 127;
      p2[(((size_t)b * T_ + t) * 80 + k80) * L_ + l] = 0.f;
    }
    return;
  }

  __shared__ float smem[2 * 4096 + 2 * 2048];      // 48 KB
  float (*As)[4096] = (float(*)[4096])smem;        // [buf][128 rows x 32k]
  float (*Bs)[2048] = (float(*)[2048])(smem + 2 * 4096);  // [buf][64 x 32k]

  const int wave = tid >> 6;
  const int lane = tid & 63;
  const int lrow = lane & 15;
  const int quad = lane >> 4;
  const int wm   = wave * 32;

  // --- staging source addresses: wave stages 8 rows/instr, 16B-chunk
  // swizzled on the GLOBAL side (chunk ^= row&7) since LDS dst is linear.
  const int lr8 = lane >> 3;
  const int sw  = (lane & 7) ^ lr8;
  const float* ga[4];
  #pragma unroll
  for (int i = 0; i < 4; ++i) {
    int row = wave * 32 + i * 8 + lr8;
    ga[i] = lig_feat + ((size_t)(b * L_ + row) * E_ + e) * F_ + sw * 4;
  }
  const float* gb[2];
  #pragma unroll
  for (int i = 0; i < 2; ++i) {
    int row = wave * 16 + i * 8 + lr8;
    gb[i] = rec_feat + ((size_t)(b * R_ + r0 + row) * E_ + e) * F_ + sw * 4;
  }

  floatx4 acc[2][4];
  #pragma unroll
  for (int i = 0; i < 2; ++i)
    #pragma unroll
    for (int j = 0; j < 4; ++j)
      acc[i][j] = (floatx4){0.f, 0.f, 0.f, 0.f};

  // fragment-read physical chunks (row&7 == lane&7 for all fragment rows)
  const int c0 = (2 * quad) ^ (lane & 7);

  // stage chunk 0 -> buf 0
  #pragma unroll
  for (int i = 0; i < 4; ++i) stage16(ga[i], &As[0][(wave * 32 + i * 8) * 32]);
  #pragma unroll
  for (int i = 0; i < 2; ++i) stage16(gb[i], &Bs[0][(wave * 16 + i * 8) * 32]);
  __syncthreads();

  #pragma unroll 1
  for (int kc = 0; kc < 16; ++kc) {
    const int cur = kc & 1;
    if (kc < 15) {
      const int col = (kc + 1) * 32;
      #pragma unroll
      for (int i = 0; i < 4; ++i)
        stage16(ga[i] + col, &As[cur ^ 1][(wave * 32 + i * 8) * 32]);
      #pragma unroll
      for (int i = 0; i < 2; ++i)
        stage16(gb[i] + col, &Bs[cur ^ 1][(wave * 16 + i * 8) * 32]);
    }
    short8 af[2], bfv[4];
    #pragma unroll
    for (int i = 0; i < 2; ++i) {
      const float* base = &As[cur][(wm + i * 16 + lrow) * 32];
      af[i] = pack8(*(const floatx4*)(base + c0 * 4),
                    *(const floatx4*)(base + (c0 ^ 1) * 4));
    }
    #pragma unroll
    for (int j = 0; j < 4; ++j) {
      const float* base = &Bs[cur][(j * 16 + lrow) * 32];
      bfv[j] = pack8(*(const floatx4*)(base + c0 * 4),
                     *(const floatx4*)(base + (c0 ^ 1) * 4));
    }
    #pragma unroll
    for (int i = 0; i < 2; ++i)
      #pragma unroll
      for (int j = 0; j < 4; ++j)
        acc[i][j] = __builtin_amdgcn_mfma_f32_16x16x32_bf16(af[i], bfv[j], acc[i][j], 0, 0, 0);
    __syncthreads();
  }

  // ---- epilogue: distance-weighted reduction over this tile's 64 r ----
  // reuse As region for new_lig tile, padded to float4 per (t,l)
  float* nls4 = smem;                 // [t*128+l]*4, 32 KB
  __syncthreads();                    // (redundant with loop-end barrier; cheap)
  for (int idx = tid; idx < T_ * L_; idx += 256) {
    const float* src = new_lig + (size_t)b * T_ * L_ * 3 + idx * 3;
    nls4[idx * 4 + 0] = src[0];
    nls4[idx * 4 + 1] = src[1];
    nls4[idx * 4 + 2] = src[2];
  }
  __syncthreads();

  const int ligN = lig_counts[b];
  float rx[4], ry[4], rz[4];
  #pragma unroll
  for (int j = 0; j < 4; ++j) {
    int r = r0 + j * 16 + lrow;
    const float* rc = rec_coord + ((size_t)b * R_ + r) * 3;
    rx[j] = rc[0]; ry[j] = rc[1]; rz[j] = rc[2];
    const float rmsk = (r < recN) ? 1.f : 0.f;   // zero masked-pair atn
    #pragma unroll
    for (int i = 0; i < 2; ++i) acc[i][j] *= rmsk;
  }

  // block-uniform switch on e -> 5 instantiations
  #define EPILOGUE(EXP)                                                        \
    _Pragma("unroll 1")                                                        \
    for (int t = 0; t < T_; ++t) {                                             \
      _Pragma("unroll")                                                        \
      for (int i = 0; i < 2; ++i) {                                            \
        _Pragma("unroll")                                                      \
        for (int reg = 0; reg < 4; ++reg) {                                    \
          const int l = wm + i * 16 + quad * 4 + reg;                          \
          const floatx4 nl = *(const floatx4*)&nls4[(t * L_ + l) * 4];         \
          float val = 0.f;                                                     \
          _Pragma("unroll")                                                    \
          for (int j = 0; j < 4; ++j) {                                        \
            float dx = nl[0] - rx[j];                                          \
            float dy = nl[1] - ry[j];                                          \
            float dz = nl[2] - rz[j];                                          \
            float d2 = fmaf(dx, dx, fmaf(dy, dy, dz * dz));                    \
            d2 = fmaxf(d2, 1e-20f);                                            \
            float rs = rsqrtf(d2);                                             \
            val = fmaf(acc[i][j][reg], powE<EXP>(d2, rs), val);                \
          }                                                                    \
          if (l >= ligN) val = 0.f;                                            \
          val += __shfl_xor(val, 1, 64);                                       \
          val += __shfl_xor(val, 2, 64);                                       \
          val += __shfl_xor(val, 4, 64);                                       \
          val += __shfl_xor(val, 8, 64);                                       \
          if (lrow == 0)                                                       \
            p2[(((size_t)b * T_ + t) * 80 + k80) * L_ + l] = val;              \
        }                                                                      \
      }                                                                        \
    }

  switch (e) {
    case 0: EPILOGUE(0) break;
    case 1: EPILOGUE(1) break;
    case 2: EPILOGUE(2) break;
    case 3: EPILOGUE(3) break;
    default: EPILOGUE(4) break;
  }
  #undef EPILOGUE
}

// ---------------------------------------------------------------------------
// Kernel 3: out[b,t] = sum_{k<80, l<128} p2[b,t,k,l]
// 128 blocks x 128 threads; thread l sums its 80-slice column (coalesced).
// ---------------------------------------------------------------------------
__global__ void final_kernel(const float* __restrict__ p2,
                             float* __restrict__ out) {
  const int bt = blockIdx.x;
  const int l = threadIdx.x;
  const float* p = p2 + (size_t)bt * 80 * L_ + l;
  float v = 0.f;
  #pragma unroll
  for (int k = 0; k < 80; ++k) v += p[k * L_];
  #pragma unroll
  for (int m = 32; m > 0; m >>= 1) v += __shfl_xor(v, m, 64);
  __shared__ float s[2];
  if ((l & 63) == 0) s[l >> 6] = v;
  __syncthreads();
  if (l == 0) out[bt] = s[0] + s[1];
}

// ---------------------------------------------------------------------------
extern "C" void kernel_launch(void* const* d_in, const int* in_sizes, int n_in,
                              void* d_out, int out_size, void* d_ws, size_t ws_size,
                              hipStream_t stream) {
  const float* lig_feat   = (const float*)d_in[0];
  const float* rec_feat   = (const float*)d_in[1];
  const float* lig_coord  = (const float*)d_in[2];
  const float* rec_coord  = (const float*)d_in[3];
  const float* pre_rot    = (const float*)d_in[4];
  const float* trans      = (const float*)d_in[5];
  const int*   lig_counts = (const int*)d_in[6];
  const int*   rec_counts = (const int*)d_in[7];
  float* out = (float*)d_out;

  // ws: new_lig [B,T,L,3] (24 KB) | p2 [B,T,80,L] (5.24 MB)
  float* new_lig = (float*)d_ws;
  float* p2      = new_lig + (size_t)B_ * T_ * L_ * 3;

  prep_kernel<<<dim3(B_ * T_), dim3(L_), 0, stream>>>(lig_coord, pre_rot, trans, new_lig);
  fused_kernel<<<dim3(R_ / 64, E_, B_), dim3(256), 0, stream>>>(
      lig_feat, rec_feat, new_lig, rec_coord, lig_counts, rec_counts, p2);
  final_kernel<<<dim3(B_ * T_), dim3(128), 0, stream>>>(p2, out);
}